// Round 4
// baseline (802.085 us; speedup 1.0000x reference)
//
#include <hip/hip_runtime.h>
#include <math.h>

#define BB 8
#define LL 1024
#define EE 512
#define HH 8
#define HD 64
#define PP 2047

static constexpr float SCALE = 0.04419417382415922f; // 1/sqrt(512)

typedef __bf16 bf16x8 __attribute__((ext_vector_type(8)));
typedef float f32x4 __attribute__((ext_vector_type(4)));
typedef unsigned short u16;
typedef u16 u16x8 __attribute__((ext_vector_type(8)));
typedef u16 u16x4 __attribute__((ext_vector_type(4)));

#define MFMA16(a, b, c) __builtin_amdgcn_mfma_f32_16x16x32_bf16(a, b, c, 0, 0, 0)

static __device__ __forceinline__ unsigned short f2bfbits(float f) {
    union { float f; unsigned u; } v; v.f = f;
    unsigned r = v.u + 0x7fffu + ((v.u >> 16) & 1u);
    return (unsigned short)(r >> 16);
}
static __device__ __forceinline__ float bfbits2f(unsigned short b) {
    union { unsigned u; float f; } v; v.u = ((unsigned)b) << 16;
    return v.f;
}

static __device__ __forceinline__ u16x8 cvt8(float4 lo, float4 hi) {
    u16x8 r;
    r[0] = f2bfbits(lo.x); r[1] = f2bfbits(lo.y);
    r[2] = f2bfbits(lo.z); r[3] = f2bfbits(lo.w);
    r[4] = f2bfbits(hi.x); r[5] = f2bfbits(hi.y);
    r[6] = f2bfbits(hi.z); r[7] = f2bfbits(hi.w);
    return r;
}

// async global(16B/lane) -> LDS, wave-uniform LDS base + lane*16
static __device__ __forceinline__ void gload_lds16(const u16* g, u16* l) {
    __builtin_amdgcn_global_load_lds(
        (const __attribute__((address_space(1))) unsigned int*)g,
        (__attribute__((address_space(3))) unsigned int*)l, 16, 0, 0);
}

// wave-local LDS fence: cross-lane LDS visibility within one wave (lockstep),
// no block barrier. Rule #18: sched_barrier after inline-asm lgkmcnt.
static __device__ __forceinline__ void wave_fence() {
    asm volatile("s_waitcnt lgkmcnt(0)" ::: "memory");
    __builtin_amdgcn_sched_barrier(0);
}

// ---------------------------------------------------------------------------
// Fused one-shot fp32 -> bf16 cast of all GEMM inputs.
// cum: x 4194304 | pe 1048064 | ipw 786432 | lpw 262144 | opw 262144
// ---------------------------------------------------------------------------
__global__ __launch_bounds__(256) void cast_all(
    const float* __restrict__ x, const float* __restrict__ pe,
    const float* __restrict__ ipw, const float* __restrict__ lpw,
    const float* __restrict__ opw,
    u16* __restrict__ Xb, u16* __restrict__ Pb, u16* __restrict__ Wqb,
    u16* __restrict__ Wpb, u16* __restrict__ Wob)
{
    size_t e = ((size_t)blockIdx.x * 256 + threadIdx.x) * 8;
    const float* src; u16* dst; size_t off;
    if (e < 4194304)      { src = x;   dst = Xb;  off = e; }
    else if (e < 5242368) { src = pe;  dst = Pb;  off = e - 4194304; }
    else if (e < 6028800) { src = ipw; dst = Wqb; off = e - 5242368; }
    else if (e < 6290944) { src = lpw; dst = Wpb; off = e - 6028800; }
    else if (e < 6553088) { src = opw; dst = Wob; off = e - 6290944; }
    else return;
    float4 lo = *(const float4*)&src[off];
    float4 hi = *(const float4*)&src[off + 4];
    *(u16x8*)&dst[off] = cvt8(lo, hi);
}

// ---------------------------------------------------------------------------
// bf16 MFMA mainloop: C(128x128) = A(128xK) . B(128xK)^T rows, K=512.
// global_load_lds(16B) staging, linear LDS dest, XOR-swizzled global source
// + matching XOR on ds_read side (rule: both-sides-or-neither).
// acc[mt][nt][r] = C[m0 + wr*64 + mt*16 + g*4 + r][n0 + wc*64 + nt*16 + c16]
// ---------------------------------------------------------------------------
template<bool CLAMP>
static __device__ __forceinline__ void gemm128b(
    const u16* __restrict__ Ab, const u16* __restrict__ Bb,
    int m0, int n0, int amax, u16* As, u16* Bs, f32x4 (&acc)[4][4])
{
    const int tid = threadIdx.x;
    const int w = tid >> 6, lane = tid & 63;
    const int g = lane >> 4, c16 = lane & 15;
    const int wr = w >> 1, wc = w & 1;

#pragma unroll
    for (int i = 0; i < 4; i++)
#pragma unroll
        for (int j = 0; j < 4; j++) acc[i][j] = (f32x4){0.f, 0.f, 0.f, 0.f};

    // staging geometry: 16B unit U = j*256 + tid; row = U>>3, col-unit = U&7,
    // source col-unit swizzled by row&7; LDS stays linear (HW lane*16 order).
    int arow[4], brow[4], cs8[4], ldsu[4];
#pragma unroll
    for (int j = 0; j < 4; j++) {
        int U = j * 256 + tid;
        int row = U >> 3, cu = U & 7;
        cs8[j] = (cu ^ (row & 7)) * 8;
        int ar = m0 + row;
        if (CLAMP) ar = ar > amax ? amax : ar;
        arow[j] = ar;
        brow[j] = n0 + row;
        ldsu[j] = (j * 256 + (w << 6)) * 8; // wave-uniform LDS base (u16 elems)
    }

    for (int kt = 0; kt < EE; kt += 64) {
#pragma unroll
        for (int j = 0; j < 4; j++) {
            gload_lds16(Ab + (size_t)arow[j] * EE + kt + cs8[j], As + ldsu[j]);
            gload_lds16(Bb + (size_t)brow[j] * EE + kt + cs8[j], Bs + ldsu[j]);
        }
        __syncthreads(); // drains vmcnt -> tiles resident
#pragma unroll
        for (int kk = 0; kk < 2; kk++) {
            bf16x8 av[4], bv[4];
#pragma unroll
            for (int mt = 0; mt < 4; mt++) {
                int r0 = wr * 64 + mt * 16 + c16;
                av[mt] = *(const bf16x8*)&As[r0 * 64 + (((kk * 4 + g) ^ (r0 & 7)) << 3)];
            }
#pragma unroll
            for (int nt = 0; nt < 4; nt++) {
                int r0 = wc * 64 + nt * 16 + c16;
                bv[nt] = *(const bf16x8*)&Bs[r0 * 64 + (((kk * 4 + g) ^ (r0 & 7)) << 3)];
            }
#pragma unroll
            for (int mt = 0; mt < 4; mt++)
#pragma unroll
                for (int nt = 0; nt < 4; nt++)
                    acc[mt][nt] = MFMA16(av[mt], bv[nt], acc[mt][nt]);
        }
        __syncthreads(); // all reads done before next stage overwrites
    }
}

// ---------------------------------------------------------------------------
// merged qkv + posk. 1-D grid of 832 blocks:
//   bid < 768: qkv tile, XCD-clustered m-range. V-class outputs are written
//              via an LDS transpose (coalesced 16B Vt rows) instead of
//              scattered 2B stores (was ~30x write amplification).
//   bid >= 768: posk tile (64 blocks)
// ---------------------------------------------------------------------------
__global__ __launch_bounds__(256) void qkvpos_kernel(
    const u16* __restrict__ xb,       // (B*L, E) bf16
    const u16* __restrict__ wq,       // (3E, E) bf16
    const float* __restrict__ ubias,  // flat 512
    const float* __restrict__ vbias,  // flat 512
    unsigned short* __restrict__ Qu,  // (B,H,L,HD) bf16, (q+u)*scale
    unsigned short* __restrict__ Qv,  // (B,H,L,HD) bf16, (q+v)*scale
    unsigned short* __restrict__ Kw,  // (B,H,L,HD) bf16
    unsigned short* __restrict__ Vt,  // (B,H,HD,L) bf16 (transposed!)
    const u16* __restrict__ peb,      // (P, E) bf16
    const u16* __restrict__ wp,       // (E, E) bf16
    unsigned short* __restrict__ pko) // (H, P, HD) bf16
{
    __shared__ u16 S[2 * 128 * 64];   // As | Bs; reused as [128][128] V-transpose buf
    u16* As = S;
    u16* Bs = S + 128 * 64;
    const int bid = blockIdx.x;
    const int tid = threadIdx.x;
    const int w = tid >> 6, lane = tid & 63;
    const int g = lane >> 4, c16 = lane & 15;
    const int wr = w >> 1, wc = w & 1;
    f32x4 acc[4][4];

    if (bid < 768) {
        const int xcd = bid & 7, j = bid >> 3;
        const int m0 = (xcd * 8 + j / 12) * 128, n0 = (j % 12) * 128;
        gemm128b<false>(xb, wq, m0, n0, 0, As, Bs, acc);
        // direct writes for Q/K; V staged to LDS transposed (XOR-swizzled cols)
#pragma unroll
        for (int mt = 0; mt < 4; mt++) {
#pragma unroll
            for (int r = 0; r < 4; r++) {
                int m = m0 + wr * 64 + mt * 16 + g * 4 + r;
                int b = m >> 10, l = m & 1023;
#pragma unroll
                for (int nt = 0; nt < 4; nt++) {
                    int n = n0 + wc * 64 + nt * 16 + c16;
                    int h = n / 192;
                    int rr = n - h * 192;
                    int cls = rr >> 6;
                    int d = rr & 63;
                    float v = acc[mt][nt][r];
                    if (cls == 0) {
                        size_t idx = ((size_t)(b * HH + h) * LL + l) * HD + d;
                        Qu[idx] = f2bfbits((v + ubias[h * 64 + d]) * SCALE);
                        Qv[idx] = f2bfbits((v + vbias[h * 64 + d]) * SCALE);
                    } else if (cls == 1) {
                        Kw[((size_t)(b * HH + h) * LL + l) * HD + d] = f2bfbits(v);
                    } else {
                        int nl = n - n0;           // 0..127
                        int ml = m - m0;           // 0..127
                        S[nl * 128 + (ml ^ ((nl & 7) << 3))] = f2bfbits(v);
                    }
                }
            }
        }
        __syncthreads();
        // coalesced Vt writeout: 16 rows/pass x 8 passes, 16B per lane
        const int b0 = m0 >> 10, l0 = m0 & 1023;
#pragma unroll
        for (int pp = 0; pp < 8; pp++) {
            int nl = pp * 16 + (tid >> 4);
            int n = n0 + nl;
            int h = n / 192, rr = n - h * 192;
            if (rr >= 128) {
                int d = rr & 63, mu = tid & 15;
                u16x8 vv = *(const u16x8*)&S[nl * 128 + ((mu * 8) ^ ((nl & 7) << 3))];
                *(u16x8*)&Vt[((size_t)(b0 * HH + h) * HD + d) * LL + l0 + mu * 8] = vv;
            }
        }
    } else {
        const int j = bid - 768;
        const int m0 = (j >> 2) * 128, n0 = (j & 3) * 128;
        gemm128b<true>(peb, wp, m0, n0, PP - 1, As, Bs, acc);
#pragma unroll
        for (int mt = 0; mt < 4; mt++) {
#pragma unroll
            for (int r = 0; r < 4; r++) {
                int p = m0 + wr * 64 + mt * 16 + g * 4 + r;
                if (p >= PP) continue;
#pragma unroll
                for (int nt = 0; nt < 4; nt++) {
                    int n = n0 + wc * 64 + nt * 16 + c16;
                    int h = n >> 6, d = n & 63;
                    pko[((size_t)h * PP + p) * HD + d] = f2bfbits(acc[mt][nt][r]);
                }
            }
        }
    }
}

// ---------------------------------------------------------------------------
// outproj: (B*L,E)bf16 @ (E,E)^T bf16 + bias -> fp32 out. XCD-clustered.
// ---------------------------------------------------------------------------
__global__ __launch_bounds__(256) void outproj_kernel(
    const u16* __restrict__ ctxb,   // (B*L, E) bf16
    const u16* __restrict__ wo,     // (E, E) bf16
    const float* __restrict__ bias, // (E,)
    float* __restrict__ out)        // (B*L, E)
{
    __shared__ u16 S[2 * 128 * 64];
    const int bid = blockIdx.x;
    const int xcd = bid & 7, j = bid >> 3;
    const int m0 = (xcd * 8 + (j >> 2)) * 128, n0 = (j & 3) * 128;
    f32x4 acc[4][4];
    gemm128b<false>(ctxb, wo, m0, n0, 0, S, S + 128 * 64, acc);

    const int tid = threadIdx.x;
    const int w = tid >> 6, lane = tid & 63;
    const int g = lane >> 4, c16 = lane & 15;
    const int wr = w >> 1, wc = w & 1;

#pragma unroll
    for (int mt = 0; mt < 4; mt++) {
#pragma unroll
        for (int r = 0; r < 4; r++) {
            int m = m0 + wr * 64 + mt * 16 + g * 4 + r;
#pragma unroll
            for (int nt = 0; nt < 4; nt++) {
                int n = n0 + wc * 64 + nt * 16 + c16;
                out[(size_t)m * EE + n] = acc[mt][nt][r] + bias[n];
            }
        }
    }
}

// ---------------------------------------------------------------------------
// MFMA fused attention, TWO-PASS online-softmax (register diet: no resident
// 1024-key logit row). 1-D grid 4096, XCD-clustered. 4 waves k-split 256 ea.
// Pass A: stream 16 k-tiles, keep only per-half (max,sum). Pass B: recompute
// logits, write normalized attn, PV per 32-col pair. Wave-private LDS with
// wave fences; only 2 block barriers (softmax combine + ctx reduction).
// ---------------------------------------------------------------------------
__global__ __launch_bounds__(256, 5) void attn_kernel(
    const u16* __restrict__ Qu, const u16* __restrict__ Qv,
    const u16* __restrict__ Kw, const u16* __restrict__ Vt,
    const u16* __restrict__ pk,  // (H,P,HD) bf16
    float* __restrict__ attn,    // (B,H,L,L)
    u16* __restrict__ ctxb)      // (B,L,E) bf16
{
    const int bid = blockIdx.x;
    const int xcd = bid & 7, jj = bid >> 3;
    const int bh = xcd * 8 + (jj >> 6);
    const int q0 = (jj & 63) * 16;
    const int b = bh >> 3, h = bh & 7;
    const int tid = threadIdx.x;
    const int w = tid >> 6, lane = tid & 63;
    const int g = lane >> 4, c16 = lane & 15;

    __shared__ __align__(16) u16 BDG[4][16 * 152];  // per-wave BD window / CTX alias
    __shared__ __align__(16) u16 PBUF[4][16 * 40];  // per-wave P-pair staging
    __shared__ float SMmax[4][16];
    __shared__ float SMsum[4][16];
    u16* BDGw = BDG[w];
    u16* PBw  = PBUF[w];

    // resident A-fragments (A[m=lane&15][k=g*8+j]): direct 16B global loads
    const u16* qub = Qu + ((size_t)bh * LL + q0 + c16) * HD + g * 8;
    const u16* qvb = Qv + ((size_t)bh * LL + q0 + c16) * HD + g * 8;
    bf16x8 au0 = *(const bf16x8*)qub;
    bf16x8 au1 = *(const bf16x8*)(qub + 32);
    bf16x8 av0 = *(const bf16x8*)qvb;
    bf16x8 av1 = *(const bf16x8*)(qvb + 32);

    const u16* kbase  = Kw + (size_t)bh * LL * HD;
    const u16* pkbase = pk + (size_t)h * PP * HD;

    // ---- pass A: streaming stats ----
    float mh[2][4], sh[2][4];
#pragma unroll
    for (int p = 0; p < 2; p++) {
        const int kp = w * 256 + p * 128;
        const int pstart = kp - q0 + 1008;
#pragma unroll
        for (int ct = 0; ct < 9; ct++) {
            int prow = pstart + ct * 16 + c16;
            prow = prow > (PP - 1) ? (PP - 1) : prow;  // col 143 pad, never gathered
            const u16* pb = pkbase + (size_t)prow * HD + g * 8;
            f32x4 acc = (f32x4){0.f, 0.f, 0.f, 0.f};
            acc = MFMA16(av0, *(const bf16x8*)pb, acc);
            acc = MFMA16(av1, *(const bf16x8*)(pb + 32), acc);
#pragma unroll
            for (int r = 0; r < 4; r++)
                BDGw[(g * 4 + r) * 152 + ct * 16 + c16] = f2bfbits(acc[r]);
        }
        wave_fence();
        f32x4 t8[8];
#pragma unroll
        for (int jt = 0; jt < 8; jt++) {
            const u16* kb = kbase + (size_t)(kp + jt * 16 + c16) * HD + g * 8;
            t8[jt] = (f32x4){0.f, 0.f, 0.f, 0.f};
            t8[jt] = MFMA16(au0, *(const bf16x8*)kb, t8[jt]);
            t8[jt] = MFMA16(au1, *(const bf16x8*)(kb + 32), t8[jt]);
        }
#pragma unroll
        for (int jt = 0; jt < 8; jt++)
#pragma unroll
            for (int r = 0; r < 4; r++) {
                int i = g * 4 + r;
                t8[jt][r] += bfbits2f(BDGw[i * 152 + jt * 16 + c16 - i + 15]);
            }
#pragma unroll
        for (int r = 0; r < 4; r++) {
            float m = t8[0][r];
#pragma unroll
            for (int jt = 1; jt < 8; jt++) m = fmaxf(m, t8[jt][r]);
            float s = 0.f;
#pragma unroll
            for (int jt = 0; jt < 8; jt++) s += __expf(t8[jt][r] - m);
            mh[p][r] = m;
            sh[p][r] = s;
        }
        wave_fence();  // gather reads done before next p overwrites BDGw
    }

    // ---- combine halves -> lanes -> waves ----
    float M[4], Sv[4], inv[4];
#pragma unroll
    for (int r = 0; r < 4; r++) {
        float m2 = fmaxf(mh[0][r], mh[1][r]);
        Sv[r] = sh[0][r] * __expf(mh[0][r] - m2) + sh[1][r] * __expf(mh[1][r] - m2);
        M[r] = m2;
    }
#pragma unroll
    for (int off = 8; off >= 1; off >>= 1)
#pragma unroll
        for (int r = 0; r < 4; r++) {
            float mo = __shfl_xor(M[r], off, 16);
            float so = __shfl_xor(Sv[r], off, 16);
            float mn = fmaxf(M[r], mo);
            Sv[r] = Sv[r] * __expf(M[r] - mn) + so * __expf(mo - mn);
            M[r] = mn;
        }
    if (c16 == 0) {
#pragma unroll
        for (int r = 0; r < 4; r++) {
            SMmax[w][g * 4 + r] = M[r];
            SMsum[w][g * 4 + r] = Sv[r];
        }
    }
    __syncthreads();
#pragma unroll
    for (int r = 0; r < 4; r++) {
        int row = g * 4 + r;
        float ma = SMmax[0][row], mb = SMmax[1][row];
        float mc = SMmax[2][row], md = SMmax[3][row];
        float mm = fmaxf(fmaxf(ma, mb), fmaxf(mc, md));
        float ss = SMsum[0][row] * __expf(ma - mm) + SMsum[1][row] * __expf(mb - mm)
                 + SMsum[2][row] * __expf(mc - mm) + SMsum[3][row] * __expf(md - mm);
        M[r] = mm;
        inv[r] = 1.0f / ss;
    }

    // ---- pass B: recompute, write attn, PV ----
    f32x4 cacc[4];
#pragma unroll
    for (int nt = 0; nt < 4; nt++) cacc[nt] = (f32x4){0.f, 0.f, 0.f, 0.f};
    float* arow = attn + (size_t)bh * LL * LL;

#pragma unroll
    for (int p = 0; p < 2; p++) {
        const int kp = w * 256 + p * 128;
        const int pstart = kp - q0 + 1008;
#pragma unroll
        for (int ct = 0; ct < 9; ct++) {
            int prow = pstart + ct * 16 + c16;
            prow = prow > (PP - 1) ? (PP - 1) : prow;
            const u16* pb = pkbase + (size_t)prow * HD + g * 8;
            f32x4 acc = (f32x4){0.f, 0.f, 0.f, 0.f};
            acc = MFMA16(av0, *(const bf16x8*)pb, acc);
            acc = MFMA16(av1, *(const bf16x8*)(pb + 32), acc);
#pragma unroll
            for (int r = 0; r < 4; r++)
                BDGw[(g * 4 + r) * 152 + ct * 16 + c16] = f2bfbits(acc[r]);
        }
        wave_fence();
#pragma unroll
        for (int jt2 = 0; jt2 < 4; jt2++) {
#pragma unroll
            for (int e = 0; e < 2; e++) {
                int jt = jt2 * 2 + e;
                const u16* kb = kbase + (size_t)(kp + jt * 16 + c16) * HD + g * 8;
                f32x4 t = (f32x4){0.f, 0.f, 0.f, 0.f};
                t = MFMA16(au0, *(const bf16x8*)kb, t);
                t = MFMA16(au1, *(const bf16x8*)(kb + 32), t);
#pragma unroll
                for (int r = 0; r < 4; r++) {
                    int i = g * 4 + r;
                    float s = t[r] + bfbits2f(BDGw[i * 152 + jt * 16 + c16 - i + 15]);
                    float pr = __expf(s - M[r]) * inv[r];
                    arow[(size_t)(q0 + i) * LL + kp + jt * 16 + c16] = pr;
                    PBw[i * 40 + e * 16 + c16] = f2bfbits(pr);
                }
            }
            wave_fence();
            bf16x8 pa = *(const bf16x8*)&PBw[c16 * 40 + g * 8];
#pragma unroll
            for (int nt = 0; nt < 4; nt++) {
                const u16* vb = Vt + ((size_t)bh * HD + nt * 16 + c16) * LL
                              + kp + jt2 * 32 + g * 8;
                cacc[nt] = MFMA16(pa, *(const bf16x8*)vb, cacc[nt]);
            }
            wave_fence();  // PV reads done before next pair overwrites PBw
        }
    }

    // ---- cross-wave ctx reduction (CTX aliases own BDG region) ----
    {
        float* CTXw = (float*)BDGw;
#pragma unroll
        for (int nt = 0; nt < 4; nt++)
#pragma unroll
            for (int r = 0; r < 4; r++)
                CTXw[(g * 4 + r) * 68 + nt * 16 + c16] = cacc[nt][r];
    }
    __syncthreads();
    {
        int row = tid >> 4, d4 = (tid & 15) * 4;
        f32x4 s = *(const f32x4*)&((const float*)BDG[0])[row * 68 + d4];
        s += *(const f32x4*)&((const float*)BDG[1])[row * 68 + d4];
        s += *(const f32x4*)&((const float*)BDG[2])[row * 68 + d4];
        s += *(const f32x4*)&((const float*)BDG[3])[row * 68 + d4];
        u16x4 o;
        o[0] = f2bfbits(s[0]); o[1] = f2bfbits(s[1]);
        o[2] = f2bfbits(s[2]); o[3] = f2bfbits(s[3]);
        *(u16x4*)&ctxb[((size_t)b * LL + q0 + row) * EE + h * HD + d4] = o;
    }
}

// ---------------------------------------------------------------------------
extern "C" void kernel_launch(void* const* d_in, const int* in_sizes, int n_in,
                              void* d_out, int out_size, void* d_ws, size_t ws_size,
                              hipStream_t stream)
{
    const float* x   = (const float*)d_in[0];
    const float* pe  = (const float*)d_in[1];
    const float* ipw = (const float*)d_in[2];
    const float* lpw = (const float*)d_in[3];
    const float* opw = (const float*)d_in[4];
    const float* opb = (const float*)d_in[5];
    const float* pbu = (const float*)d_in[6];
    const float* pbv = (const float*)d_in[7];

    float* out  = (float*)d_out;                          // (B,L,E)
    float* attn = (float*)d_out + (size_t)BB * LL * EE;   // (B,H,L,L)

    const size_t NQ = (size_t)BB * HH * LL * HD;  // 4194304
    u16* wsu  = (u16*)d_ws;
    u16* ctxb = wsu; wsu += (size_t)BB * LL * EE;         // 4194304
    u16* Qu   = wsu; wsu += NQ;
    u16* Qv   = wsu; wsu += NQ;
    u16* Kw   = wsu; wsu += NQ;
    u16* Vt   = wsu; wsu += NQ;
    u16* pkb  = wsu; wsu += (size_t)HH * PP * HD;         // 1048064
    u16* Xb   = wsu; wsu += 4194304;                      // (B*L,E) bf16
    u16* Pb   = wsu; wsu += 1048064;                      // (P,E) bf16
    u16* Wqb  = wsu; wsu += 786432;                       // (3E,E) bf16
    u16* Wpb  = wsu; wsu += 262144;                       // (E,E) bf16
    u16* Wob  = wsu; wsu += 262144;                       // (E,E) bf16

    cast_all<<<3200, 256, 0, stream>>>(x, pe, ipw, lpw, opw, Xb, Pb, Wqb, Wpb, Wob);
    qkvpos_kernel<<<832, 256, 0, stream>>>(Xb, Wqb, pbu, pbv, Qu, Qv, Kw, Vt,
                                           Pb, Wpb, pkb);
    attn_kernel<<<4096, 256, 0, stream>>>(Qu, Qv, Kw, Vt, pkb, attn, ctxb);
    outproj_kernel<<<256, 256, 0, stream>>>(ctxb, Wob, opb, out);
}

// Round 5
// 511.598 us; speedup vs baseline: 1.5678x; 1.5678x over previous
//
#include <hip/hip_runtime.h>
#include <math.h>

#define BB 8
#define LL 1024
#define EE 512
#define HH 8
#define HD 64
#define PP 2047

static constexpr float SCALE = 0.04419417382415922f; // 1/sqrt(512)

typedef __bf16 bf16x8 __attribute__((ext_vector_type(8)));
typedef float f32x4 __attribute__((ext_vector_type(4)));
typedef unsigned short u16;
typedef u16 u16x8 __attribute__((ext_vector_type(8)));
typedef u16 u16x4 __attribute__((ext_vector_type(4)));

#define MFMA16(a, b, c) __builtin_amdgcn_mfma_f32_16x16x32_bf16(a, b, c, 0, 0, 0)

static __device__ __forceinline__ unsigned short f2bfbits(float f) {
    union { float f; unsigned u; } v; v.f = f;
    unsigned r = v.u + 0x7fffu + ((v.u >> 16) & 1u);
    return (unsigned short)(r >> 16);
}
static __device__ __forceinline__ float bfbits2f(unsigned short b) {
    union { unsigned u; float f; } v; v.u = ((unsigned)b) << 16;
    return v.f;
}

static __device__ __forceinline__ u16x8 cvt8(float4 lo, float4 hi) {
    u16x8 r;
    r[0] = f2bfbits(lo.x); r[1] = f2bfbits(lo.y);
    r[2] = f2bfbits(lo.z); r[3] = f2bfbits(lo.w);
    r[4] = f2bfbits(hi.x); r[5] = f2bfbits(hi.y);
    r[6] = f2bfbits(hi.z); r[7] = f2bfbits(hi.w);
    return r;
}

// async global(16B/lane) -> LDS, wave-uniform LDS base + lane*16
static __device__ __forceinline__ void gload_lds16(const u16* g, u16* l) {
    __builtin_amdgcn_global_load_lds(
        (const __attribute__((address_space(1))) unsigned int*)g,
        (__attribute__((address_space(3))) unsigned int*)l, 16, 0, 0);
}

// wave-local LDS fence: cross-lane LDS visibility within one wave (lockstep),
// no block barrier, and crucially NO vmcnt drain (global stores stay async).
// Rule #18: sched_barrier after inline-asm lgkmcnt.
static __device__ __forceinline__ void wave_fence() {
    asm volatile("s_waitcnt lgkmcnt(0)" ::: "memory");
    __builtin_amdgcn_sched_barrier(0);
}

// ---------------------------------------------------------------------------
// Fused one-shot fp32 -> bf16 cast of all GEMM inputs.
// ---------------------------------------------------------------------------
__global__ __launch_bounds__(256) void cast_all(
    const float* __restrict__ x, const float* __restrict__ pe,
    const float* __restrict__ ipw, const float* __restrict__ lpw,
    const float* __restrict__ opw,
    u16* __restrict__ Xb, u16* __restrict__ Pb, u16* __restrict__ Wqb,
    u16* __restrict__ Wpb, u16* __restrict__ Wob)
{
    size_t e = ((size_t)blockIdx.x * 256 + threadIdx.x) * 8;
    const float* src; u16* dst; size_t off;
    if (e < 4194304)      { src = x;   dst = Xb;  off = e; }
    else if (e < 5242368) { src = pe;  dst = Pb;  off = e - 4194304; }
    else if (e < 6028800) { src = ipw; dst = Wqb; off = e - 5242368; }
    else if (e < 6290944) { src = lpw; dst = Wpb; off = e - 6028800; }
    else if (e < 6553088) { src = opw; dst = Wob; off = e - 6290944; }
    else return;
    float4 lo = *(const float4*)&src[off];
    float4 hi = *(const float4*)&src[off + 4];
    *(u16x8*)&dst[off] = cvt8(lo, hi);
}

// ---------------------------------------------------------------------------
// bf16 MFMA mainloop, 2-PHASE double-buffered: one barrier per K-step; the
// stage of tile t+1 is issued before computing tile t (T3-minimum pattern).
// S layout: [buf0 As | buf0 Bs | buf1 As | buf1 Bs], 8192 u16 each (64KB).
// acc[mt][nt][r] = C[m0 + wr*64 + mt*16 + g*4 + r][n0 + wc*64 + nt*16 + c16]
// ---------------------------------------------------------------------------
template<bool CLAMP>
static __device__ __forceinline__ void gemm128b(
    const u16* __restrict__ Ab, const u16* __restrict__ Bb,
    int m0, int n0, int amax, u16* S, f32x4 (&acc)[4][4])
{
    const int tid = threadIdx.x;
    const int w = tid >> 6, lane = tid & 63;
    const int g = lane >> 4, c16 = lane & 15;
    const int wr = w >> 1, wc = w & 1;

#pragma unroll
    for (int i = 0; i < 4; i++)
#pragma unroll
        for (int j = 0; j < 4; j++) acc[i][j] = (f32x4){0.f, 0.f, 0.f, 0.f};

    // staging geometry: 16B unit U = j*256 + tid; row = U>>3, col-unit = U&7,
    // source col-unit swizzled by row&7; LDS stays linear (HW lane*16 order).
    int arow[4], brow[4], cs8[4], ldsu[4];
#pragma unroll
    for (int j = 0; j < 4; j++) {
        int U = j * 256 + tid;
        int row = U >> 3, cu = U & 7;
        cs8[j] = (cu ^ (row & 7)) * 8;
        int ar = m0 + row;
        if (CLAMP) ar = ar > amax ? amax : ar;
        arow[j] = ar;
        brow[j] = n0 + row;
        ldsu[j] = (j * 256 + (w << 6)) * 8; // wave-uniform LDS base (u16 elems)
    }

    // prologue: stage kt=0 into buf0
#pragma unroll
    for (int j = 0; j < 4; j++) {
        gload_lds16(Ab + (size_t)arow[j] * EE + cs8[j], S + ldsu[j]);
        gload_lds16(Bb + (size_t)brow[j] * EE + cs8[j], S + 8192 + ldsu[j]);
    }
    __syncthreads();

#pragma unroll
    for (int t = 0; t < 8; t++) {
        const u16* cb = S + ((t & 1) ? 16384 : 0);
        u16* nb = S + ((t & 1) ? 0 : 16384);
        if (t < 7) {
            const int kt = (t + 1) * 64;
#pragma unroll
            for (int j = 0; j < 4; j++) {
                gload_lds16(Ab + (size_t)arow[j] * EE + kt + cs8[j], nb + ldsu[j]);
                gload_lds16(Bb + (size_t)brow[j] * EE + kt + cs8[j], nb + 8192 + ldsu[j]);
            }
        }
        const u16* As = cb;
        const u16* Bs = cb + 8192;
#pragma unroll
        for (int kk = 0; kk < 2; kk++) {
            bf16x8 av[4], bv[4];
#pragma unroll
            for (int mt = 0; mt < 4; mt++) {
                int r0 = wr * 64 + mt * 16 + c16;
                av[mt] = *(const bf16x8*)&As[r0 * 64 + (((kk * 4 + g) ^ (r0 & 7)) << 3)];
            }
#pragma unroll
            for (int nt = 0; nt < 4; nt++) {
                int r0 = wc * 64 + nt * 16 + c16;
                bv[nt] = *(const bf16x8*)&Bs[r0 * 64 + (((kk * 4 + g) ^ (r0 & 7)) << 3)];
            }
#pragma unroll
            for (int mt = 0; mt < 4; mt++)
#pragma unroll
                for (int nt = 0; nt < 4; nt++)
                    acc[mt][nt] = MFMA16(av[mt], bv[nt], acc[mt][nt]);
        }
        __syncthreads(); // drains: stage of t+1 done; reads of t done
    }
}

// ---------------------------------------------------------------------------
// merged qkv + posk. 1-D grid of 832 blocks (XCD-clustered qkv part).
// V-class outputs go through an LDS transpose for coalesced 16B Vt rows.
// ---------------------------------------------------------------------------
__global__ __launch_bounds__(256) void qkvpos_kernel(
    const u16* __restrict__ xb, const u16* __restrict__ wq,
    const float* __restrict__ ubias, const float* __restrict__ vbias,
    unsigned short* __restrict__ Qu, unsigned short* __restrict__ Qv,
    unsigned short* __restrict__ Kw, unsigned short* __restrict__ Vt,
    const u16* __restrict__ peb, const u16* __restrict__ wp,
    unsigned short* __restrict__ pko)
{
    __shared__ u16 S[4 * 8192];   // 64KB: gemm dbuf; reused as V-transpose buf
    const int bid = blockIdx.x;
    const int tid = threadIdx.x;
    const int w = tid >> 6, lane = tid & 63;
    const int g = lane >> 4, c16 = lane & 15;
    const int wr = w >> 1, wc = w & 1;
    f32x4 acc[4][4];

    if (bid < 768) {
        const int xcd = bid & 7, j = bid >> 3;
        const int m0 = (xcd * 8 + j / 12) * 128, n0 = (j % 12) * 128;
        gemm128b<false>(xb, wq, m0, n0, 0, S, acc);
#pragma unroll
        for (int mt = 0; mt < 4; mt++) {
#pragma unroll
            for (int r = 0; r < 4; r++) {
                int m = m0 + wr * 64 + mt * 16 + g * 4 + r;
                int b = m >> 10, l = m & 1023;
#pragma unroll
                for (int nt = 0; nt < 4; nt++) {
                    int n = n0 + wc * 64 + nt * 16 + c16;
                    int h = n / 192;
                    int rr = n - h * 192;
                    int cls = rr >> 6;
                    int d = rr & 63;
                    float v = acc[mt][nt][r];
                    if (cls == 0) {
                        size_t idx = ((size_t)(b * HH + h) * LL + l) * HD + d;
                        Qu[idx] = f2bfbits((v + ubias[h * 64 + d]) * SCALE);
                        Qv[idx] = f2bfbits((v + vbias[h * 64 + d]) * SCALE);
                    } else if (cls == 1) {
                        Kw[((size_t)(b * HH + h) * LL + l) * HD + d] = f2bfbits(v);
                    } else {
                        int nl = n - n0;           // 0..127
                        int ml = m - m0;           // 0..127
                        S[nl * 128 + (ml ^ ((nl & 7) << 3))] = f2bfbits(v);
                    }
                }
            }
        }
        __syncthreads();
        // coalesced Vt writeout: 16 rows/pass x 8 passes, 16B per lane
        const int b0 = m0 >> 10, l0 = m0 & 1023;
#pragma unroll
        for (int pp = 0; pp < 8; pp++) {
            int nl = pp * 16 + (tid >> 4);
            int n = n0 + nl;
            int h = n / 192, rr = n - h * 192;
            if (rr >= 128) {
                int d = rr & 63, mu = tid & 15;
                u16x8 vv = *(const u16x8*)&S[nl * 128 + ((mu * 8) ^ ((nl & 7) << 3))];
                *(u16x8*)&Vt[((size_t)(b0 * HH + h) * HD + d) * LL + l0 + mu * 8] = vv;
            }
        }
    } else {
        const int j = bid - 768;
        const int m0 = (j >> 2) * 128, n0 = (j & 3) * 128;
        gemm128b<true>(peb, wp, m0, n0, PP - 1, S, acc);
#pragma unroll
        for (int mt = 0; mt < 4; mt++) {
#pragma unroll
            for (int r = 0; r < 4; r++) {
                int p = m0 + wr * 64 + mt * 16 + g * 4 + r;
                if (p >= PP) continue;
#pragma unroll
                for (int nt = 0; nt < 4; nt++) {
                    int n = n0 + wc * 64 + nt * 16 + c16;
                    int h = n >> 6, d = n & 63;
                    pko[((size_t)h * PP + p) * HD + d] = f2bfbits(acc[mt][nt][r]);
                }
            }
        }
    }
}

// ---------------------------------------------------------------------------
// outproj: (B*L,E)bf16 @ (E,E)^T bf16 + bias -> fp32 out. XCD-clustered.
// ---------------------------------------------------------------------------
__global__ __launch_bounds__(256) void outproj_kernel(
    const u16* __restrict__ ctxb, const u16* __restrict__ wo,
    const float* __restrict__ bias, float* __restrict__ out)
{
    __shared__ u16 S[4 * 8192];
    const int bid = blockIdx.x;
    const int xcd = bid & 7, j = bid >> 3;
    const int m0 = (xcd * 8 + (j >> 2)) * 128, n0 = (j & 3) * 128;
    f32x4 acc[4][4];
    gemm128b<false>(ctxb, wo, m0, n0, 0, S, acc);

    const int tid = threadIdx.x;
    const int w = tid >> 6, lane = tid & 63;
    const int g = lane >> 4, c16 = lane & 15;
    const int wr = w >> 1, wc = w & 1;

#pragma unroll
    for (int mt = 0; mt < 4; mt++) {
#pragma unroll
        for (int r = 0; r < 4; r++) {
            int m = m0 + wr * 64 + mt * 16 + g * 4 + r;
#pragma unroll
            for (int nt = 0; nt < 4; nt++) {
                int n = n0 + wc * 64 + nt * 16 + c16;
                out[(size_t)m * EE + n] = acc[mt][nt][r] + bias[n];
            }
        }
    }
}

// ---------------------------------------------------------------------------
// MFMA fused attention, SINGLE-PASS (lg resident), barrier diet: wave-private
// LDS + lgkmcnt-only fences; exactly 2 block barriers (softmax combine, CTX
// reduction). No vmcnt drain between attn stores and PV -> stores stay async.
// 1-D grid 4096, XCD-clustered. 4 waves k-split 256 each.
// ---------------------------------------------------------------------------
__global__ __launch_bounds__(256, 4) void attn_kernel(
    const u16* __restrict__ Qu, const u16* __restrict__ Qv,
    const u16* __restrict__ Kw, const u16* __restrict__ Vt,
    const u16* __restrict__ pk,  // (H,P,HD) bf16
    float* __restrict__ attn,    // (B,H,L,L)
    u16* __restrict__ ctxb)      // (B,L,E) bf16
{
    const int bid = blockIdx.x;
    const int xcd = bid & 7, jj = bid >> 3;
    const int bh = xcd * 8 + (jj >> 6);
    const int q0 = (jj & 63) * 16;
    const int b = bh >> 3, h = bh & 7;
    const int tid = threadIdx.x;
    const int w = tid >> 6, lane = tid & 63;
    const int g = lane >> 4, c16 = lane & 15;

    __shared__ __align__(16) u16 BDG[4][16 * 152];  // per-wave BD / P-stage / CTX
    __shared__ float SMmax[4][16];
    __shared__ float SMsum[4][16];
    u16* BDGw = BDG[w];

    // resident A-fragments (A[m=lane&15][k=g*8+j]): direct 16B global loads
    const u16* qub = Qu + ((size_t)bh * LL + q0 + c16) * HD + g * 8;
    const u16* qvb = Qv + ((size_t)bh * LL + q0 + c16) * HD + g * 8;
    bf16x8 au0 = *(const bf16x8*)qub;
    bf16x8 au1 = *(const bf16x8*)(qub + 32);
    bf16x8 av0 = *(const bf16x8*)qvb;
    bf16x8 av1 = *(const bf16x8*)(qvb + 32);

    f32x4 lg[16];
#pragma unroll
    for (int t = 0; t < 16; t++) lg[t] = (f32x4){0.f, 0.f, 0.f, 0.f};

    const u16* kbase  = Kw + (size_t)bh * LL * HD;
    const u16* pkbase = pk + (size_t)h * PP * HD;

#pragma unroll
    for (int p = 0; p < 2; p++) {
        const int kp = w * 256 + p * 128;
        const int pstart = kp - q0 + 1008;  // window col 0 -> p index
        // BD window gemm: 16 q x 144 cols, staged bf16 in wave-private LDS
#pragma unroll
        for (int ct = 0; ct < 9; ct++) {
            int prow = pstart + ct * 16 + c16;
            prow = prow > (PP - 1) ? (PP - 1) : prow;  // col 143 pad, never gathered
            const u16* pb = pkbase + (size_t)prow * HD + g * 8;
            f32x4 acc = (f32x4){0.f, 0.f, 0.f, 0.f};
            acc = MFMA16(av0, *(const bf16x8*)pb, acc);
            acc = MFMA16(av1, *(const bf16x8*)(pb + 32), acc);
#pragma unroll
            for (int r = 0; r < 4; r++)
                BDGw[(g * 4 + r) * 152 + ct * 16 + c16] = f2bfbits(acc[r]);
        }
        wave_fence();
        // AC: B-frag = K rows, direct global 16B loads
#pragma unroll
        for (int jt = 0; jt < 8; jt++) {
            const u16* kb = kbase + (size_t)(kp + jt * 16 + c16) * HD + g * 8;
            int t = p * 8 + jt;
            lg[t] = MFMA16(au0, *(const bf16x8*)kb, lg[t]);
            lg[t] = MFMA16(au1, *(const bf16x8*)(kb + 32), lg[t]);
        }
        // diagonal gather: BD[i][j] = BDG[i][j - i + 15]
#pragma unroll
        for (int jt = 0; jt < 8; jt++) {
            int t = p * 8 + jt;
#pragma unroll
            for (int r = 0; r < 4; r++) {
                int i = g * 4 + r;
                lg[t][r] += bfbits2f(BDGw[i * 152 + jt * 16 + c16 - i + 15]);
            }
        }
        wave_fence();  // gather reads done before next p overwrites BDGw
    }

    // ---- softmax: per-wave (m,s), ONE barrier, online cross-wave merge ----
    float Mw[4], Sv[4], fac[4];
#pragma unroll
    for (int r = 0; r < 4; r++) {
        float m = lg[0][r];
#pragma unroll
        for (int t = 1; t < 16; t++) m = fmaxf(m, lg[t][r]);
        Mw[r] = m;
    }
#pragma unroll
    for (int off = 8; off >= 1; off >>= 1)
#pragma unroll
        for (int r = 0; r < 4; r++) Mw[r] = fmaxf(Mw[r], __shfl_xor(Mw[r], off, 16));
#pragma unroll
    for (int r = 0; r < 4; r++) Sv[r] = 0.f;
#pragma unroll
    for (int t = 0; t < 16; t++)
#pragma unroll
        for (int r = 0; r < 4; r++) {
            float e = __expf(lg[t][r] - Mw[r]);
            lg[t][r] = e;               // lg now holds exp(s - m_wave)
            Sv[r] += e;
        }
#pragma unroll
    for (int off = 8; off >= 1; off >>= 1)
#pragma unroll
        for (int r = 0; r < 4; r++) Sv[r] += __shfl_xor(Sv[r], off, 16);
    if (c16 == 0) {
#pragma unroll
        for (int r = 0; r < 4; r++) {
            SMmax[w][g * 4 + r] = Mw[r];
            SMsum[w][g * 4 + r] = Sv[r];
        }
    }
    __syncthreads();  // block barrier #1
#pragma unroll
    for (int r = 0; r < 4; r++) {
        int row = g * 4 + r;
        float ma = SMmax[0][row], mb = SMmax[1][row];
        float mc = SMmax[2][row], md = SMmax[3][row];
        float mm = fmaxf(fmaxf(ma, mb), fmaxf(mc, md));
        float ss = SMsum[0][row] * __expf(ma - mm) + SMsum[1][row] * __expf(mb - mm)
                 + SMsum[2][row] * __expf(mc - mm) + SMsum[3][row] * __expf(md - mm);
        fac[r] = __expf(Mw[r] - mm) / ss;   // lg * fac = normalized prob
    }

    // ---- normalize + write attn (plain async stores; nothing drains them) ----
    float* arow = attn + (size_t)bh * LL * LL;
#pragma unroll
    for (int t = 0; t < 16; t++)
#pragma unroll
        for (int r = 0; r < 4; r++) {
            float pr = lg[t][r] * fac[r];
            lg[t][r] = pr;
            arow[(size_t)(q0 + g * 4 + r) * LL + w * 256 + t * 16 + c16] = pr;
        }

    // ---- PV: ctx[q][d] = sum_k P[q,k] V[k,d], B from transposed V ----
    f32x4 cacc[4];
#pragma unroll
    for (int nt = 0; nt < 4; nt++) cacc[nt] = (f32x4){0.f, 0.f, 0.f, 0.f};

#pragma unroll
    for (int p = 0; p < 2; p++) {
        const int kp = w * 256 + p * 128;
        // stage P (C-layout -> A-layout via wave-private LDS), bf16
#pragma unroll
        for (int jt = 0; jt < 8; jt++) {
            int t = p * 8 + jt;
#pragma unroll
            for (int r = 0; r < 4; r++)
                BDGw[(g * 4 + r) * 152 + jt * 16 + c16] = f2bfbits(lg[t][r]);
        }
        wave_fence();
        bf16x8 pa[4];
#pragma unroll
        for (int kk = 0; kk < 4; kk++)
            pa[kk] = *(const bf16x8*)&BDGw[c16 * 152 + kk * 32 + g * 8];
#pragma unroll
        for (int kk = 0; kk < 4; kk++) {
#pragma unroll
            for (int nt = 0; nt < 4; nt++) {
                const u16* vb = Vt + ((size_t)bh * HD + nt * 16 + c16) * LL
                              + kp + kk * 32 + g * 8;
                cacc[nt] = MFMA16(pa[kk], *(const bf16x8*)vb, cacc[nt]);
            }
        }
        wave_fence();  // pa reads complete before next p / CTX overwrite
    }

    // ---- cross-wave ctx reduction (CTX aliases own BDG region) ----
    {
        float* CTXw = (float*)BDGw;
#pragma unroll
        for (int nt = 0; nt < 4; nt++)
#pragma unroll
            for (int r = 0; r < 4; r++)
                CTXw[(g * 4 + r) * 68 + nt * 16 + c16] = cacc[nt][r];
    }
    __syncthreads();  // block barrier #2
    {
        int row = tid >> 4, d4 = (tid & 15) * 4;
        f32x4 s = *(const f32x4*)&((const float*)BDG[0])[row * 68 + d4];
        s += *(const f32x4*)&((const float*)BDG[1])[row * 68 + d4];
        s += *(const f32x4*)&((const float*)BDG[2])[row * 68 + d4];
        s += *(const f32x4*)&((const float*)BDG[3])[row * 68 + d4];
        u16x4 o;
        o[0] = f2bfbits(s[0]); o[1] = f2bfbits(s[1]);
        o[2] = f2bfbits(s[2]); o[3] = f2bfbits(s[3]);
        *(u16x4*)&ctxb[((size_t)b * LL + q0 + row) * EE + h * HD + d4] = o;
    }
}

// ---------------------------------------------------------------------------
extern "C" void kernel_launch(void* const* d_in, const int* in_sizes, int n_in,
                              void* d_out, int out_size, void* d_ws, size_t ws_size,
                              hipStream_t stream)
{
    const float* x   = (const float*)d_in[0];
    const float* pe  = (const float*)d_in[1];
    const float* ipw = (const float*)d_in[2];
    const float* lpw = (const float*)d_in[3];
    const float* opw = (const float*)d_in[4];
    const float* opb = (const float*)d_in[5];
    const float* pbu = (const float*)d_in[6];
    const float* pbv = (const float*)d_in[7];

    float* out  = (float*)d_out;                          // (B,L,E)
    float* attn = (float*)d_out + (size_t)BB * LL * EE;   // (B,H,L,L)

    const size_t NQ = (size_t)BB * HH * LL * HD;  // 4194304
    u16* wsu  = (u16*)d_ws;
    u16* ctxb = wsu; wsu += (size_t)BB * LL * EE;         // 4194304
    u16* Qu   = wsu; wsu += NQ;
    u16* Qv   = wsu; wsu += NQ;
    u16* Kw   = wsu; wsu += NQ;
    u16* Vt   = wsu; wsu += NQ;
    u16* pkb  = wsu; wsu += (size_t)HH * PP * HD;         // 1048064
    u16* Xb   = wsu; wsu += 4194304;                      // (B*L,E) bf16
    u16* Pb   = wsu; wsu += 1048064;                      // (P,E) bf16
    u16* Wqb  = wsu; wsu += 786432;                       // (3E,E) bf16
    u16* Wpb  = wsu; wsu += 262144;                       // (E,E) bf16
    u16* Wob  = wsu; wsu += 262144;                       // (E,E) bf16

    cast_all<<<3200, 256, 0, stream>>>(x, pe, ipw, lpw, opw, Xb, Pb, Wqb, Wpb, Wob);
    qkvpos_kernel<<<832, 256, 0, stream>>>(Xb, Wqb, pbu, pbv, Qu, Qv, Kw, Vt,
                                           Pb, Wpb, pkb);
    attn_kernel<<<4096, 256, 0, stream>>>(Qu, Qv, Kw, Vt, pkb, attn, ctxb);
    outproj_kernel<<<256, 256, 0, stream>>>(ctxb, Wob, opb, out);
}